// Round 9
// baseline (320.793 us; speedup 1.0000x reference)
//
#include <hip/hip_runtime.h>
#include <hip/hip_bf16.h>
#include <cstddef>
#include <cstdint>

#define B_    16
#define CIN_  256
#define COUT_ 128
#define H_    64
#define W_    64
#define OH_   128
#define OW_   128

// Dense A rows: 32 shorts (64 B). Bank spread via baked XOR swizzle
// byte_off' = byte_off ^ ((row&7)<<4) applied at synth-write and read.
#define ACH   4096                // shorts per (cls,chunk) A slice (8192 B)

typedef __attribute__((ext_vector_type(8))) short bf16x8;
typedef __attribute__((ext_vector_type(4))) float f32x4;

__device__ inline short f2bf(float f) {
    __hip_bfloat16 h = __float2bfloat16(f);
    return *reinterpret_cast<short*>(&h);
}

__device__ inline int packbf(float lo, float hi) {
    unsigned a = (unsigned short)f2bf(lo);
    unsigned b = (unsigned short)f2bf(hi);
    return (int)(a | (b << 16));
}

__device__ inline void async_ld16(const void* g, void* l) {
    typedef const __attribute__((address_space(1))) unsigned int* gp_t;
    typedef __attribute__((address_space(3))) unsigned int* lp_t;
    __builtin_amdgcn_global_load_lds((gp_t)g, (lp_t)l, 16, 0, 0);
}

// ---------------------------------------------------------------------------
// Synth body: weights are b-invariant -> load once into REGISTERS, loop b.
// Block = (chunk, cog8): 8 ci x 8 co x 16 k slice. Per b: compute, stage in
// 2KB LDS, copy-out int2 to the dense SWIZZLED aws layout.
// ---------------------------------------------------------------------------
__device__ inline void synth_body(
    int chunk, int cog8, int tid,
    const float* __restrict__ weight,
    const float* __restrict__ tb, const float* __restrict__ tq,
    const float* __restrict__ tn, const float* __restrict__ tx,
    const float* __restrict__ mb, const float* __restrict__ mq,
    const float* __restrict__ mn, const float* __restrict__ mx,
    const float* __restrict__ feat,
    short* __restrict__ aws,
    short* lbuf /* [4 cls][8 co][32 k] shorts = 2KB */)
{
    const int ci_l = tid >> 5;          // 0..7
    const int co_l = (tid >> 2) & 7;    // 0..7
    const int kh   = tid & 3;           // 0..3
    const int base = (chunk*8 + ci_l) * COUT_ + cog8*8 + co_l;

    const float4 w4 = *(const float4*)(weight + (size_t)base*16 + kh*4);
    const float4 b4 = *(const float4*)(tb + (size_t)base*16 + kh*4);
    const float4 q4 = *(const float4*)(tq + (size_t)base*16 + kh*4);
    const float4 n4 = *(const float4*)(tn + (size_t)base*16 + kh*4);
    const float4 x4 = *(const float4*)(tx + (size_t)base*16 + kh*4);
    const float m_b = mb[base], m_q = mq[base];
    const float m_n = mn[base], m_x = mx[base];
    const float* wp = (const float*)&w4;
    const float* bp = (const float*)&b4;
    const float* qp = (const float*)&q4;
    const float* np = (const float*)&n4;
    const float* xp = (const float*)&x4;

    const int r  = (kh+1)&1;
    const int dh = (kh<2) ? 1 : 0;

    const int o_cls = tid >> 6;
    const int o_cor = (tid >> 3) & 7;
    const int o_e8  = tid & 7;
    const int o_off = (((cog8*8 + o_cor)*64 + o_e8*8) ^ (o_cor << 4)); // bytes

    for (int b = 0; b < 16; ++b) {
        const float sb = m_b * feat[b*4+0];
        const float sq = m_q * feat[b*4+1];
        const float sn = m_n * feat[b*4+2];
        const float sx = m_x * feat[b*4+3];
        #pragma unroll
        for (int kw = 0; kw < 4; ++kw) {
            int s  = (kw+1)&1;
            int dw = (kw<2) ? 1 : 0;
            float v = wp[kw] + sb*bp[kw] + sq*qp[kw] + sn*np[kw] + sx*xp[kw];
            lbuf[((r*2+s)*8 + co_l)*32 + (dh*2+dw)*8 + ci_l] = f2bf(v);
        }
        __syncthreads();
        {
            size_t sbase = ((size_t)(b*4 + o_cls)*32 + chunk) * ACH;
            *(int2*)(aws + sbase + (o_off >> 1)) =
                *(const int2*)(lbuf + (o_cls*8 + o_cor)*32 + o_e8*4);
        }
        __syncthreads();
    }
}

// grid (32, 16): chunk x cog8
__global__ __launch_bounds__(256) void synth_aws(
    const float* __restrict__ weight,
    const float* __restrict__ tb, const float* __restrict__ tq,
    const float* __restrict__ tn, const float* __restrict__ tx,
    const float* __restrict__ mb, const float* __restrict__ mq,
    const float* __restrict__ mn, const float* __restrict__ mx,
    const float* __restrict__ feat,
    short* __restrict__ aws)
{
    __shared__ __align__(16) short lbuf[4][8][32];
    synth_body(blockIdx.x, blockIdx.y, threadIdx.x, weight, tb, tq, tn, tx,
               mb, mq, mn, mx, feat, aws, &lbuf[0][0][0]);
}

// ---------------------------------------------------------------------------
// Kernel C v7b: transform_x ELIMINATED. B tile (9 rows x 33 cols x 8 ci bf16)
// gathered from x (fp32) with T14 async split:
//   syncthreads -> issue A-DMA(c+1) -> issue B scalar gathers(c+1) to regs ->
//   MFMA(c) -> cvt+ds_write(c+1) -> loop.
// v7b fixes: (1) left-halo off-by-one (when iw0=-1, tile-col1 takes x[0]=p[0],
// not p[1]); (2) scalar dword loads (odd iw0 made float2 4B-aligned: UB).
// ---------------------------------------------------------------------------
__global__ __launch_bounds__(256, 2) void deconv_mfma7(
    const float* __restrict__ x,
    const short* __restrict__ aws,
    const float* __restrict__ bias, const float* __restrict__ prelu_a,
    float* __restrict__ out)
{
    const int tid  = threadIdx.x;
    const int lane = tid & 63;
    const int wv   = tid >> 6;
    const int wm   = wv & 1, wn = wv >> 1;
    const int o    = blockIdx.x;              // 0..1023
    const int x8   = o & 7;
    const int l    = o >> 3;                  // 0..127
    const int cls  = l & 3;
    const int nt2  = (l >> 2) & 15;
    const int b    = 2*x8 + (l >> 6);
    const int a0 = (nt2 >> 1) * 8, c0 = (nt2 & 1) * 32;
    const int r = cls >> 1, s = cls & 1;

    __shared__ __align__(16) short als[2][2*ACH];   // A: 2 bufs x 16KB
    __shared__ __align__(16) short xsb[2][2*2560];  // B: 2 bufs x 2 halves x [9][33][8]

    // ---- A-DMA plan: 16 transfers/double-chunk, t = wv + i*4 ----
    const size_t awb = (((size_t)b*4 + cls)*32) * ACH;
    const short* ga  = aws + awb + wv*512 + lane*8;

    // ---- B gather init (main pass: tile cols 0..31) ----
    const int col2 = tid & 15;           // tile cols {2c2, 2c2+1}
    const int cip  = (tid >> 4) & 3;     // ci {2cip, 2cip+1}
    const int rowg = wv;                 // rows {0,1},{2,3},{4,5},{6,7,8}
    const int row_base = (rowg < 3) ? rowg*2 : 6;
    const int nrows    = (rowg < 3) ? 2 : 3;
    const int iw0  = c0 + s - 1 + 2*col2;          // -1..62
    const int ok0  = (iw0 >= 0);
    const int iwc  = ok0 ? iw0 : 0;
    const int ihb  = a0 + r - 1;                   // -1..56
    int rv[3];
    #pragma unroll
    for (int j = 0; j < 3; ++j) {
        int ih = ihb + row_base + j;
        rv[j] = (j < nrows) && (ih >= 0) && (ih < 64);
    }
    const float* xg = x + ((size_t)b*256 + 2*cip)*4096 + iwc;

    // ---- B gather init (tail: tile col 32) ----
    const int tl  = (tid < 144);
    const int tt  = tl ? tid : 0;
    const int half_t = (tt >= 72) ? 1 : 0;
    const int rem_t  = tt - 72*half_t;
    const int row_t  = rem_t >> 3, ci_t = rem_t & 7;
    const int iw_t   = c0 + s + 31;                // 31,32,63,64
    const int ih_t   = ihb + row_t;
    const int okt    = tl && (iw_t < 64) && (ih_t >= 0) && (ih_t < 64);
    const int iht_c  = (ih_t < 0) ? 0 : ((ih_t > 63) ? 63 : ih_t);
    const int iwt_c  = (iw_t > 63) ? 63 : iw_t;
    const size_t tbase = ((size_t)b*256 + half_t*8 + ci_t)*4096 + iht_c*64 + iwt_c;
    const int lwt = ((row_t*33 + 32)*8 + ci_t) + half_t*2560;

    f32x4 acc[4][8];
    #pragma unroll
    for (int mi = 0; mi < 4; ++mi)
        #pragma unroll
        for (int ni = 0; ni < 8; ++ni)
            acc[mi][ni] = (f32x4){0.f, 0.f, 0.f, 0.f};

    const int nlo = lane & 15;
    const int q   = lane >> 4;
    const int dh  = q >> 1, dw = q & 1;

    // swizzled A-read offsets (shorts)
    int aoff[4];
    #pragma unroll
    for (int mi = 0; mi < 4; ++mi) {
        int row  = wm*64 + mi*16 + nlo;
        aoff[mi] = ((row*64 + q*16) ^ ((nlo & 7) << 4)) >> 1;
    }

    // ---- prologue: stage double-chunk 0 into buffer 0 ----
    #pragma unroll
    for (int i = 0; i < 4; ++i)
        async_ld16(ga + i*2048, &als[0][wv*512 + i*2048]);
    {
        #pragma unroll
        for (int h = 0; h < 2; ++h)
            #pragma unroll
            for (int j = 0; j < 3; ++j) {
                float a0v = 0.f, a1v = 0.f, b0v = 0.f, b1v = 0.f;
                if (rv[j]) {
                    const float* p = xg + (size_t)(h*8)*4096
                                        + (ihb + row_base + j)*64;
                    a0v = p[0];    a1v = p[1];
                    b0v = p[4096]; b1v = p[4097];
                }
                if (j < nrows) {
                    int lb = ((row_base + j)*33 + 2*col2)*8 + 2*cip + h*2560;
                    *(int*)&xsb[0][lb]     = ok0 ? packbf(a0v, b0v) : 0;
                    *(int*)&xsb[0][lb + 8] = ok0 ? packbf(a1v, b1v)
                                                 : packbf(a0v, b0v);
                }
            }
        if (tl) {
            float tv = x[tbase];
            xsb[0][lwt] = okt ? f2bf(tv) : (short)0;
        }
    }

    for (int c = 0; c < 16; ++c) {
        __syncthreads();                 // buf[c&1] fully staged
        const int sel = c & 1;
        const int ps  = sel ^ 1;
        float ha[2][3][2], hb[2][3][2];
        float ht = 0.f;
        if (c < 15) {
            // A-DMA prefetch (stays in flight; drained at next __syncthreads)
            #pragma unroll
            for (int i = 0; i < 4; ++i)
                async_ld16(ga + (size_t)(c+1)*2*ACH + i*2048,
                           &als[ps][wv*512 + i*2048]);
            // B gather loads -> regs (latency hidden under MFMA below)
            #pragma unroll
            for (int h = 0; h < 2; ++h)
                #pragma unroll
                for (int j = 0; j < 3; ++j) {
                    ha[h][j][0] = ha[h][j][1] = 0.f;
                    hb[h][j][0] = hb[h][j][1] = 0.f;
                    if (rv[j]) {
                        const float* p = xg + ((size_t)(c+1)*16 + h*8)*4096
                                            + (ihb + row_base + j)*64;
                        ha[h][j][0] = p[0];    ha[h][j][1] = p[1];
                        hb[h][j][0] = p[4096]; hb[h][j][1] = p[4097];
                    }
                }
            if (tl) ht = x[tbase + (size_t)(c+1)*65536];
        }

        // ---- MFMA over 2 halves of double-chunk c ----
        #pragma unroll
        for (int h = 0; h < 2; ++h) {
            const short* ab = &als[sel][h*4096];
            const short* xb = &xsb[sel][h*2560];
            bf16x8 af[4], bfr[8];
            #pragma unroll
            for (int mi = 0; mi < 4; ++mi)
                af[mi] = *(const bf16x8*)(ab + aoff[mi]);
            #pragma unroll
            for (int ni = 0; ni < 8; ++ni) {
                int a_local = wn*4 + (ni & 3);
                int colx    = nlo + (ni >> 2)*16 + dw;
                bfr[ni] = *(const bf16x8*)(xb + ((a_local + dh)*33 + colx)*8);
            }
            #pragma unroll
            for (int mi = 0; mi < 4; ++mi)
                #pragma unroll
                for (int ni = 0; ni < 8; ++ni)
                    acc[mi][ni] = __builtin_amdgcn_mfma_f32_16x16x32_bf16(
                        af[mi], bfr[ni], acc[mi][ni], 0, 0, 0);
        }

        // ---- write gathered B(c+1) into xsb[ps] (loads have landed) ----
        if (c < 15) {
            #pragma unroll
            for (int h = 0; h < 2; ++h)
                #pragma unroll
                for (int j = 0; j < 3; ++j)
                    if (j < nrows) {
                        int lb = ((row_base + j)*33 + 2*col2)*8 + 2*cip + h*2560;
                        *(int*)&xsb[ps][lb]     = ok0 ? packbf(ha[h][j][0], hb[h][j][0]) : 0;
                        *(int*)&xsb[ps][lb + 8] = ok0 ? packbf(ha[h][j][1], hb[h][j][1])
                                                      : packbf(ha[h][j][0], hb[h][j][0]);
                    }
            if (tl) xsb[ps][lwt] = okt ? f2bf(ht) : (short)0;
        }
    }

    // ---- epilogue: bias + PReLU ----
    const float pa = prelu_a[0];
    #pragma unroll
    for (int mi = 0; mi < 4; ++mi) {
        #pragma unroll
        for (int reg = 0; reg < 4; ++reg) {
            int co = wm*64 + mi*16 + q*4 + reg;
            float bv = bias[co];
            #pragma unroll
            for (int ni = 0; ni < 8; ++ni) {
                int a_local = wn*4 + (ni & 3);
                int cg      = ni >> 2;
                int oh = 2*(a0 + a_local) + r;
                int ow = 2*(c0 + cg*16 + nlo) + s;
                float v = acc[mi][ni][reg] + bv;
                v = (v >= 0.f) ? v : pa*v;
                out[(((size_t)b*COUT_ + co)*OH_ + oh)*OW_ + ow] = v;
            }
        }
    }
}

// ---------------------------------------------------------------------------
// Last-resort fallback: fp32 direct kernel, in-kernel weight synthesis, no ws.
// ---------------------------------------------------------------------------
__global__ __launch_bounds__(256) void deconv_fallback(
    const float* __restrict__ x,
    const float* __restrict__ weight,
    const float* __restrict__ tb, const float* __restrict__ tq,
    const float* __restrict__ tn, const float* __restrict__ tx,
    const float* __restrict__ mb, const float* __restrict__ mq,
    const float* __restrict__ mn, const float* __restrict__ mx,
    const float* __restrict__ feat,
    const float* __restrict__ bias, const float* __restrict__ prelu_a,
    float* __restrict__ out)
{
    const int tid    = threadIdx.x;
    const int tile   = blockIdx.x;
    const int coT    = blockIdx.y;
    const int b      = blockIdx.z;
    const int tile_h = tile >> 3, tile_w = tile & 7;
    const int a0 = tile_h * 8;
    const int c0 = tile_w * 8;
    const int co0 = coT * 64;

    const int tco = tid & 15;
    const int tpx = tid >> 4;
    const int rr  = tpx >> 2, rc = tpx & 3;

    __shared__ float xsf[4][100];
    __shared__ float wsh[4][16][64];

    float acc[4][4][4];
    #pragma unroll
    for (int i = 0; i < 4; ++i)
        #pragma unroll
        for (int j = 0; j < 4; ++j)
            #pragma unroll
            for (int c = 0; c < 4; ++c) acc[i][j][c] = 0.f;

    float f0 = feat[b*4 + 0], f1 = feat[b*4 + 1];
    float f2 = feat[b*4 + 2], f3 = feat[b*4 + 3];

    for (int chunk = 0; chunk < CIN_ / 4; ++chunk) {
        const int ci0 = chunk * 4;
        __syncthreads();
        for (int e = tid; e < 400; e += 256) {
            int ci_l = e / 100; int rem = e - ci_l * 100;
            int rI = rem / 10;  int cI = rem - rI * 10;
            int ih = a0 - 1 + rI, iw = c0 - 1 + cI;
            float v = 0.f;
            if ((unsigned)ih < (unsigned)H_ && (unsigned)iw < (unsigned)W_)
                v = x[(((size_t)b * CIN_ + ci0 + ci_l) * H_ + ih) * W_ + iw];
            xsf[ci_l][rem] = v;
        }
        #pragma unroll
        for (int k = 0; k < 4; ++k) {
            int g = tid + k * 256;
            int ci_l = g >> 8; int rrem = g & 255;
            int co_l = rrem >> 2; int tg = (rrem & 3) * 4;
            int cico = (ci0 + ci_l) * COUT_ + co0 + co_l;
            int e = cico * 16 + tg;
            float4 w  = *(const float4*)(weight + e);
            float4 vb = *(const float4*)(tb + e);
            float4 vq = *(const float4*)(tq + e);
            float4 vn = *(const float4*)(tn + e);
            float4 vx = *(const float4*)(tx + e);
            float sb = mb[cico] * f0, sq = mq[cico] * f1;
            float sn = mn[cico] * f2, sx = mx[cico] * f3;
            float4 wvv;
            wvv.x = w.x + sb*vb.x + sq*vq.x + sn*vn.x + sx*vx.x;
            wvv.y = w.y + sb*vb.y + sq*vq.y + sn*vn.y + sx*vx.y;
            wvv.z = w.z + sb*vb.z + sq*vq.z + sn*vn.z + sx*vx.z;
            wvv.w = w.w + sb*vb.w + sq*vq.w + sn*vn.w + sx*vx.w;
            wsh[ci_l][tg + 0][co_l] = wvv.x;
            wsh[ci_l][tg + 1][co_l] = wvv.y;
            wsh[ci_l][tg + 2][co_l] = wvv.z;
            wsh[ci_l][tg + 3][co_l] = wvv.w;
        }
        __syncthreads();
        #pragma unroll
        for (int ci_l = 0; ci_l < 4; ++ci_l) {
            float xpv[4][4];
            #pragma unroll
            for (int i = 0; i < 4; ++i)
                #pragma unroll
                for (int j = 0; j < 4; ++j)
                    xpv[i][j] = xsf[ci_l][(rr*2 + i) * 10 + rc*2 + j];
            #pragma unroll
            for (int kh = 0; kh < 4; ++kh) {
                const int rpar = (kh & 1) ? 0 : 1;
                const int offh = (kh == 0) ? 2 : (kh == 3) ? 0 : 1;
                #pragma unroll
                for (int kw = 0; kw < 4; ++kw) {
                    const int spar = (kw & 1) ? 0 : 1;
                    const int offw = (kw == 0) ? 2 : (kw == 3) ? 0 : 1;
                    float4 wvv = *(const float4*)&wsh[ci_l][kh*4 + kw][tco*4];
                    float wr[4] = {wvv.x, wvv.y, wvv.z, wvv.w};
                    #pragma unroll
                    for (int da = 0; da < 2; ++da)
                        #pragma unroll
                        for (int dc = 0; dc < 2; ++dc) {
                            const float xvv = xpv[da + offh][dc + offw];
                            #pragma unroll
                            for (int cc = 0; cc < 4; ++cc)
                                acc[2*da + rpar][2*dc + spar][cc] =
                                    fmaf(wr[cc], xvv, acc[2*da + rpar][2*dc + spar][cc]);
                        }
                }
            }
        }
    }
    const float pa  = prelu_a[0];
    const int oh0 = tile_h * 16 + rr * 4;
    const int ow0 = tile_w * 16 + rc * 4;
    #pragma unroll
    for (int cc = 0; cc < 4; ++cc) {
        const int co = co0 + tco * 4 + cc;
        const float bv = bias[co];
        #pragma unroll
        for (int dr = 0; dr < 4; ++dr)
            #pragma unroll
            for (int dw2 = 0; dw2 < 4; ++dw2) {
                float v = acc[dr][dw2][cc] + bv;
                v = (v >= 0.f) ? v : pa * v;
                out[(((size_t)b * COUT_ + co) * OH_ + (oh0 + dr)) * OW_ + (ow0 + dw2)] = v;
            }
    }
}

extern "C" void kernel_launch(void* const* d_in, const int* in_sizes, int n_in,
                              void* d_out, int out_size, void* d_ws, size_t ws_size,
                              hipStream_t stream) {
    (void)in_sizes; (void)n_in; (void)out_size;
    const float* x      = (const float*)d_in[0];
    const float* feat   = (const float*)d_in[1];
    const float* weight = (const float*)d_in[2];
    const float* tb     = (const float*)d_in[3];
    const float* tq     = (const float*)d_in[4];
    const float* tn     = (const float*)d_in[5];
    const float* tx     = (const float*)d_in[6];
    const float* mb     = (const float*)d_in[7];
    const float* mq     = (const float*)d_in[8];
    const float* mn     = (const float*)d_in[9];
    const float* mx     = (const float*)d_in[10];
    const float* bias   = (const float*)d_in[11];
    const float* prelu  = (const float*)d_in[12];
    float* out = (float*)d_out;

    const size_t aws_sz = (size_t)B_ * 4 * 32 * ACH * sizeof(short);   // 16.78 MB

    if (ws_size >= aws_sz) {
        short* aws = (short*)d_ws;
        synth_aws<<<dim3(32, 16), 256, 0, stream>>>(
            weight, tb, tq, tn, tx, mb, mq, mn, mx, feat, aws);
        deconv_mfma7<<<dim3(1024), 256, 0, stream>>>(
            x, aws, bias, prelu, out);
    } else {
        deconv_fallback<<<dim3(64, 2, 16), 256, 0, stream>>>(
            x, weight, tb, tq, tn, tx, mb, mq, mn, mx, feat, bias, prelu, out);
    }
}